// Round 8
// baseline (918.365 us; speedup 1.0000x reference)
//
#include <hip/hip_runtime.h>

#define NN 20000
#define NE 320000
#define DIMX 256
#define NHEADS 8
#define HC 32
#define EDIMX 32
#define DFFX 1024
#define TOT (NE + NN)
#define NGROUPS (TOT / 16)  // 21250, exact

using f32x4 = __attribute__((ext_vector_type(4))) float;
using bfrag = __attribute__((ext_vector_type(8))) short;  // 8 bf16 = 4 VGPRs

__device__ __forceinline__ float b2f(unsigned short u) {
  return __uint_as_float(((unsigned)u) << 16);
}
__device__ __forceinline__ unsigned short f2b(float f) {
  unsigned u = __float_as_uint(f);
  u += 0x7FFF + ((u >> 16) & 1);
  return (unsigned short)(u >> 16);
}

// async global->LDS, 16B per lane; lds dest = wave-uniform base + lane*16
__device__ __forceinline__ void gload16(const unsigned short* g, unsigned short* l) {
  __builtin_amdgcn_global_load_lds(
      (const __attribute__((address_space(1))) unsigned int*)(g),
      (__attribute__((address_space(3))) unsigned int*)(l), 16, 0, 0);
}

// ---------------- dtype detect: 1 = inputs are f32, 0 = inputs are bf16 ----------------
__global__ void k_detect(const unsigned short* __restrict__ in, int* __restrict__ flag) {
  __shared__ int cnt_s;
  if (threadIdx.x == 0) cnt_s = 0;
  __syncthreads();
  int c = 0;
  for (int i = threadIdx.x; i < 4096; i += 256) {
    int ex = (in[i] >> 7) & 0xFF;
    if (ex >= 0xC6) c++;
  }
  atomicAdd(&cnt_s, c);
  __syncthreads();
  if (threadIdx.x == 0) flag[0] = (cnt_s > 64) ? 1 : 0;
}

// ---------------- input -> f32 + bf16 shadow ----------------
__global__ void k_cvt_dual(const void* __restrict__ in, float* __restrict__ outf,
                           unsigned short* __restrict__ outb, int n,
                           const int* __restrict__ flag) {
  int i = blockIdx.x * 256 + threadIdx.x;
  if (i >= n) return;
  if (flag[0]) {
    float v = ((const float*)in)[i];
    outf[i] = v;
    outb[i] = f2b(v);
  } else {
    unsigned short u = ((const unsigned short*)in)[i];
    outf[i] = b2f(u);
    outb[i] = u;
  }
}

// ---------------- fused multi-segment param convert ----------------
struct CvtArgs {
  const void* src[20];
  float* dst[20];
  int n[20];
};
__global__ void k_cvt_multi(CvtArgs a, const int* __restrict__ flag) {
  int seg = blockIdx.y;
  int n = a.n[seg];
  int i = blockIdx.x * 256 + threadIdx.x;
  if (i >= n) return;
  if (flag[0]) a.dst[seg][i] = ((const float*)a.src[seg])[i];
  else a.dst[seg][i] = b2f(((const unsigned short*)a.src[seg])[i]);
}

// ---------------- f32 [K][N] -> bf16 [N][K] transpose ----------------
__global__ __launch_bounds__(256) void k_transpose(const float* __restrict__ in,
                                                   unsigned short* __restrict__ out,
                                                   int K, int N) {
  __shared__ float t[32][33];
  int n0 = blockIdx.x * 32, k0 = blockIdx.y * 32;
  int tx = threadIdx.x & 31, ty = threadIdx.x >> 5;  // 32 x 8
#pragma unroll
  for (int i = 0; i < 4; i++)
    t[ty + i * 8][tx] = in[(size_t)(k0 + ty + i * 8) * N + n0 + tx];
  __syncthreads();
#pragma unroll
  for (int i = 0; i < 4; i++)
    out[(size_t)(n0 + ty + i * 8) * K + k0 + tx] = f2b(t[tx][ty + i * 8]);
}

// ---------------- edge count (int atomics only) ----------------
__global__ void k_edge_count(const int* __restrict__ dst, int* __restrict__ cnt, int E) {
  int e = blockIdx.x * 256 + threadIdx.x;
  if (e >= E) return;
  atomicAdd(&cnt[dst[e]], 1);
}

// ---------------- single-block scan -> rowptr ----------------
__global__ void k_scan(const int* __restrict__ cnt, int* __restrict__ rowptr, int N) {
  __shared__ int sums[256];
  int t = threadIdx.x;
  int chunk = (N + 255) / 256;
  int lo = t * chunk, hi = lo + chunk;
  if (hi > N) hi = N;
  if (lo > N) lo = N;
  int s = 0;
  for (int n = lo; n < hi; n++) s += cnt[n] + 1;
  sums[t] = s;
  __syncthreads();
  for (int off = 1; off < 256; off <<= 1) {
    int v = (t >= off) ? sums[t - off] : 0;
    __syncthreads();
    sums[t] += v;
    __syncthreads();
  }
  int run = sums[t] - s;  // exclusive prefix
  for (int n = lo; n < hi; n++) { rowptr[n] = run; run += cnt[n] + 1; }
  if (t == 255) rowptr[N] = run;
}

// ---------------- CSR fill (edges + self loops), also records dst per slot ----------------
__global__ void k_fill(const int* __restrict__ dst, const int* __restrict__ rowptr,
                       int* __restrict__ fill, int* __restrict__ eidx,
                       int* __restrict__ dstp, int N, int E) {
  int t = blockIdx.x * 256 + threadIdx.x;
  if (t < E) {
    int d = dst[t];
    int pos = rowptr[d] + atomicAdd(&fill[d], 1);
    eidx[pos] = t;
    dstp[pos] = d;
  } else if (t < E + N) {
    int n = t - E;
    int pos = rowptr[n + 1] - 1;
    eidx[pos] = E + n;  // self loop id
    dstp[pos] = n;
  }
}

// ---------------- loop_ea from raw ew input (flag-dispatched dtype) ----------------
__global__ __launch_bounds__(256) void k_lea(const void* __restrict__ ew,
                                             const int* __restrict__ rowptr,
                                             const int* __restrict__ eidx,
                                             float* __restrict__ lea, int N,
                                             const int* __restrict__ flag) {
  int f = flag[0];
  int wave = threadIdx.x >> 6, lane = threadIdx.x & 63;
  int node = blockIdx.x * 4 + wave;
  if (node >= N) return;
  int begin = rowptr[node], end = rowptr[node + 1] - 1;  // exclude self-loop slot
  int ch = lane & 31, half = lane >> 5;
  float s = 0.f;
  for (int p = begin + half; p < end; p += 2) {
    int eid = eidx[p];
    size_t idx = (size_t)eid * EDIMX + ch;
    s += f ? ((const float*)ew)[idx] : b2f(((const unsigned short*)ew)[idx]);
  }
  s += __shfl_xor(s, 32, 64);
  int deg = end - begin;
  if (lane < 32) lea[(size_t)node * EDIMX + ch] = s / (float)(deg > 0 ? deg : 1);
}

// ---------------- build CSR-ordered src ids + edge attrs (bf16) from raw ew ----------------
__global__ __launch_bounds__(256) void k_build_perm(const int* __restrict__ eidx,
                                                    const int* __restrict__ src,
                                                    const void* __restrict__ ew,
                                                    const float* __restrict__ lea,
                                                    int* __restrict__ srcp,
                                                    unsigned short* __restrict__ eab,
                                                    int total, int E,
                                                    const int* __restrict__ flag) {
  int f = flag[0];
  int g = blockIdx.x * 8 + (threadIdx.x >> 5);
  int lane = threadIdx.x & 31;
  if (g >= total) return;
  int eid = eidx[g];
  unsigned short v;
  int s;
  if (eid < E) {
    s = src[eid];
    size_t idx = (size_t)eid * EDIMX + lane;
    v = f ? f2b(((const float*)ew)[idx]) : ((const unsigned short*)ew)[idx];
  } else {
    s = eid - E;
    v = f2b(lea[(size_t)(eid - E) * EDIMX + lane]);
  }
  if (lane == 0) srcp[g] = s;
  eab[(size_t)g * EDIMX + lane] = v;
}

// ---------------- MFMA bf16 GEMM v3: m97 structure ----------------
template <bool BIAS, bool RELU, bool OUTBF16, int KTILES>
__global__ __launch_bounds__(256) void k_gemm_lds(const unsigned short* __restrict__ A,
                                                  const unsigned short* __restrict__ BT,
                                                  const float* __restrict__ bias,
                                                  void* __restrict__ C, int M, int N) {
  const int K = KTILES * 32;
  __shared__ unsigned short As[2][4096];  // [128 rows][32 bf16], 8KB per buf
  __shared__ unsigned short Bs[2][4096];
  int tid = threadIdx.x;
  int wave = tid >> 6, lane = tid & 63;
  int quad = lane >> 4, l16 = lane & 15;
  int wr = wave >> 1, wc = wave & 1;
  int bm0 = blockIdx.x * 128, bn0 = blockIdx.y * 128;
  int ch0 = wave * 2, ch1 = wave * 2 + 1;
  int sega = ch0 * 64 + lane, segb = ch1 * 64 + lane;
  int ra = sega >> 2, sa = sega & 3;
  int rb = segb >> 2, sb = segb & 3;
  int ca8 = sa ^ ((ra ^ (ra >> 2)) & 3);  // pre-swizzled source slot
  int cb8 = sb ^ ((rb ^ (rb >> 2)) & 3);
  int gra = bm0 + ra; if (gra > M - 1) gra = M - 1;
  int grb = bm0 + rb; if (grb > M - 1) grb = M - 1;
  const unsigned short* gA0 = A + (size_t)gra * K + ca8 * 8;
  const unsigned short* gA1 = A + (size_t)grb * K + cb8 * 8;
  const unsigned short* gB0 = BT + (size_t)(bn0 + ra) * K + ca8 * 8;
  const unsigned short* gB1 = BT + (size_t)(bn0 + rb) * K + cb8 * 8;
  f32x4 acc[4][4];
#pragma unroll
  for (int m = 0; m < 4; m++)
#pragma unroll
    for (int n = 0; n < 4; n++) acc[m][n] = (f32x4){0.f, 0.f, 0.f, 0.f};
  int sq = quad ^ ((l16 ^ (l16 >> 2)) & 3);
  int abase = (wr * 64 + l16) * 32 + sq * 8;
  int bbase = (wc * 64 + l16) * 32 + sq * 8;

  {  // stage tile 0
    gload16(gA0, &As[0][ch0 * 512]);
    gload16(gA1, &As[0][ch1 * 512]);
    gload16(gB0, &Bs[0][ch0 * 512]);
    gload16(gB1, &Bs[0][ch1 * 512]);
  }
  __syncthreads();
  int cur = 0;
  for (int t = 0; t < KTILES; ++t) {
    if (t + 1 < KTILES) {
      int ko = (t + 1) * 32;
      int nb = cur ^ 1;
      gload16(gA0 + ko, &As[nb][ch0 * 512]);
      gload16(gA1 + ko, &As[nb][ch1 * 512]);
      gload16(gB0 + ko, &Bs[nb][ch0 * 512]);
      gload16(gB1 + ko, &Bs[nb][ch1 * 512]);
    }
    bfrag af[4], bf[4];
#pragma unroll
    for (int m = 0; m < 4; m++) af[m] = *(const bfrag*)&As[cur][abase + m * 512];
#pragma unroll
    for (int n = 0; n < 4; n++) bf[n] = *(const bfrag*)&Bs[cur][bbase + n * 512];
#pragma unroll
    for (int m = 0; m < 4; m++)
#pragma unroll
      for (int n = 0; n < 4; n++)
        acc[m][n] = __builtin_amdgcn_mfma_f32_16x16x32_bf16(af[m], bf[n], acc[m][n], 0, 0, 0);
    __syncthreads();
    cur ^= 1;
  }
  int colb = bn0 + wc * 64;
  float bv[4];
#pragma unroll
  for (int n = 0; n < 4; n++) bv[n] = BIAS ? bias[colb + n * 16 + l16] : 0.f;
#pragma unroll
  for (int m = 0; m < 4; m++) {
    int row = bm0 + wr * 64 + m * 16 + quad * 4;
#pragma unroll
    for (int r = 0; r < 4; r++) {
      if (row + r < M) {
#pragma unroll
        for (int n = 0; n < 4; n++) {
          float v = acc[m][n][r] + bv[n];
          if (RELU) v = fmaxf(v, 0.f);
          int col = colb + n * 16 + l16;
          if (OUTBF16)
            ((unsigned short*)C)[(size_t)(row + r) * N + col] = f2b(v);
          else
            ((float*)C)[(size_t)(row + r) * N + col] = v;
        }
      }
    }
  }
}

// ---------------- fused GAT edge-score + softmax + aggregate (node-centric) ----------------
// One wave per CSR row (node = dst). Per 16-edge batch: EE via MFMA (per-tb staged to LDS
// to cap acc regs at 16), wave-uniform coalesced xl gathers (A/B split around MFMA), xr
// loaded ONCE per node. Per-head online softmax: lane group (lane>>3) owns head, so m/l
// are per-lane scalars; score reduce is 3 shuffles. Out accumulated in-register; no SCORE
// buffer, no second gather pass.
__global__ __launch_bounds__(256, 4) void k_gat_fused(
    const unsigned short* __restrict__ xlr, const unsigned short* __restrict__ eab,
    const int* __restrict__ srcp, const unsigned short* __restrict__ WET,
    const float* __restrict__ att, const float* __restrict__ bias,
    const int* __restrict__ rowptr, float* __restrict__ out, int N) {
  __shared__ unsigned short ee_s[4][16 * 260];  // per-wave EE slice (33.3 KB)
  int wave = threadIdx.x >> 6, lane = threadIdx.x & 63;
  int quad = lane >> 4, l16 = lane & 15;
  int node = blockIdx.x * 4 + wave;
  if (node >= N) return;  // no barrier -> safe early exit
  int begin = rowptr[node], end = rowptr[node + 1];
  int deg = end - begin;  // >= 1 (self-loop)
  int c0 = lane * 4;
  // xr for this node, loaded once (shared by all its edges)
  ushort4 xru = *(const ushort4*)(xlr + ((size_t)node << 9) + 256 + c0);
  float xr0 = b2f(xru.x), xr1 = b2f(xru.y), xr2 = b2f(xru.z), xr3 = b2f(xru.w);
  float4 a4 = *(const float4*)(att + c0);
  float m = -3.4e38f, l = 0.f;
  float o0 = 0.f, o1 = 0.f, o2 = 0.f, o3 = 0.f;

  for (int b = 0; b < deg; b += 16) {
    int pb = begin + b;
    // wave-uniform src ids (clamped to row end) -> SGPRs
    int sid[16];
#pragma unroll
    for (int i = 0; i < 16; i++) {
      int q = pb + i;
      if (q > end - 1) q = end - 1;
      sid[i] = __builtin_amdgcn_readfirstlane(srcp[q]);
    }
    // batch A xl gathers (coalesced 512B rows) issued before MFMA
    ushort4 vlA[8], vlB[8];
#pragma unroll
    for (int i = 0; i < 8; i++)
      vlA[i] = *(const ushort4*)(xlr + ((size_t)sid[i] << 9) + c0);
    // per-lane ea slot (clamped within row)
    int pe = pb + l16;
    if (pe > end - 1) pe = end - 1;
    const bfrag ea = *(const bfrag*)(eab + ((size_t)pe << 5) + quad * 8);
    // EE via MFMA, staged per-tb (acc peak 16 VGPRs)
    f32x4 zero4 = {0.f, 0.f, 0.f, 0.f};
    __builtin_amdgcn_s_setprio(1);
#pragma unroll
    for (int tb = 0; tb < 4; tb++) {
      bfrag bw[4];
#pragma unroll
      for (int j = 0; j < 4; j++)
        bw[j] = *(const bfrag*)(WET + ((tb * 4 + j) * 16 + l16) * 32 + quad * 8);
      f32x4 a0 = __builtin_amdgcn_mfma_f32_16x16x32_bf16(ea, bw[0], zero4, 0, 0, 0);
      f32x4 a1 = __builtin_amdgcn_mfma_f32_16x16x32_bf16(ea, bw[1], zero4, 0, 0, 0);
      f32x4 a2 = __builtin_amdgcn_mfma_f32_16x16x32_bf16(ea, bw[2], zero4, 0, 0, 0);
      f32x4 a3 = __builtin_amdgcn_mfma_f32_16x16x32_bf16(ea, bw[3], zero4, 0, 0, 0);
#pragma unroll
      for (int r = 0; r < 4; r++) {
        int row = (quad * 4 + r) * 260 + l16;
        ee_s[wave][row + (tb * 4 + 0) * 16] = f2b(a0[r]);
        ee_s[wave][row + (tb * 4 + 1) * 16] = f2b(a1[r]);
        ee_s[wave][row + (tb * 4 + 2) * 16] = f2b(a2[r]);
        ee_s[wave][row + (tb * 4 + 3) * 16] = f2b(a3[r]);
      }
    }
    __builtin_amdgcn_s_setprio(0);
    // batch B xl gathers (hide under score compute of batch A)
#pragma unroll
    for (int i = 0; i < 8; i++)
      vlB[i] = *(const ushort4*)(xlr + ((size_t)sid[8 + i] << 9) + c0);
    // scores: pairs; guard computes at most one extra edge (finite garbage, masked later)
    float sc[16];
    auto pair = [&](int e, const ushort4& u0, const ushort4& u1, float& s0, float& s1) {
      ushort4 eu0 = *(const ushort4*)&ee_s[wave][e * 260 + c0];
      ushort4 eu1 = *(const ushort4*)&ee_s[wave][(e + 1) * 260 + c0];
      float z00 = b2f(u0.x) + xr0 + b2f(eu0.x);
      float z01 = b2f(u0.y) + xr1 + b2f(eu0.y);
      float z02 = b2f(u0.z) + xr2 + b2f(eu0.z);
      float z03 = b2f(u0.w) + xr3 + b2f(eu0.w);
      float z10 = b2f(u1.x) + xr0 + b2f(eu1.x);
      float z11 = b2f(u1.y) + xr1 + b2f(eu1.y);
      float z12 = b2f(u1.z) + xr2 + b2f(eu1.z);
      float z13 = b2f(u1.w) + xr3 + b2f(eu1.w);
      z00 = fmaxf(z00, 0.2f * z00); z01 = fmaxf(z01, 0.2f * z01);
      z02 = fmaxf(z02, 0.2f * z02); z03 = fmaxf(z03, 0.2f * z03);
      z10 = fmaxf(z10, 0.2f * z10); z11 = fmaxf(z11, 0.2f * z11);
      z12 = fmaxf(z12, 0.2f * z12); z13 = fmaxf(z13, 0.2f * z13);
      float d0 = z00 * a4.x + z01 * a4.y + z02 * a4.z + z03 * a4.w;
      float d1 = z10 * a4.x + z11 * a4.y + z12 * a4.z + z13 * a4.w;
      d0 += __shfl_xor(d0, 1, 64);
      d1 += __shfl_xor(d1, 1, 64);
      d0 += __shfl_xor(d0, 2, 64);
      d1 += __shfl_xor(d1, 2, 64);
      d0 += __shfl_xor(d0, 4, 64);
      d1 += __shfl_xor(d1, 4, 64);
      s0 = d0;  // head (lane>>3) sum, resident in this lane
      s1 = d1;
    };
    pair(0, vlA[0], vlA[1], sc[0], sc[1]);
    if (b + 2 < deg) pair(2, vlA[2], vlA[3], sc[2], sc[3]);
    if (b + 4 < deg) pair(4, vlA[4], vlA[5], sc[4], sc[5]);
    if (b + 6 < deg) pair(6, vlA[6], vlA[7], sc[6], sc[7]);
    if (b + 8 < deg) pair(8, vlB[0], vlB[1], sc[8], sc[9]);
    if (b + 10 < deg) pair(10, vlB[2], vlB[3], sc[10], sc[11]);
    if (b + 12 < deg) pair(12, vlB[4], vlB[5], sc[12], sc[13]);
    if (b + 14 < deg) pair(14, vlB[6], vlB[7], sc[14], sc[15]);
    // batch max (valid edges only; per-lane = per-head)
    float bm = sc[0];
#define BMX(i) if (b + i < deg) bm = fmaxf(bm, sc[i]);
    BMX(1) BMX(2) BMX(3) BMX(4) BMX(5) BMX(6) BMX(7)
    BMX(8) BMX(9) BMX(10) BMX(11) BMX(12) BMX(13) BMX(14) BMX(15)
#undef BMX
    float mn = fmaxf(m, bm);
    float f = __expf(m - mn);  // first batch: exp(-inf)=0, state all zero -> fine
    o0 *= f; o1 *= f; o2 *= f; o3 *= f;
    l *= f;
    m = mn;
    // accumulate valid edges (reuse gathered xl)
#define ACCE(i, u)                                     \
  if (b + i < deg) {                                   \
    float wgt = __expf(sc[i] - m);                     \
    l += wgt;                                          \
    o0 += wgt * b2f(u.x); o1 += wgt * b2f(u.y);        \
    o2 += wgt * b2f(u.z); o3 += wgt * b2f(u.w);        \
  }
    ACCE(0, vlA[0]) ACCE(1, vlA[1]) ACCE(2, vlA[2]) ACCE(3, vlA[3])
    ACCE(4, vlA[4]) ACCE(5, vlA[5]) ACCE(6, vlA[6]) ACCE(7, vlA[7])
    ACCE(8, vlB[0]) ACCE(9, vlB[1]) ACCE(10, vlB[2]) ACCE(11, vlB[3])
    ACCE(12, vlB[4]) ACCE(13, vlB[5]) ACCE(14, vlB[6]) ACCE(15, vlB[7])
#undef ACCE
  }
  float linv = 1.f / l;
  float4 bia = *(const float4*)(bias + c0);
  ((float4*)out)[(size_t)node * 64 + lane] =
      make_float4(o0 * linv + bia.x, o1 * linv + bia.y, o2 * linv + bia.z, o3 * linv + bia.w);
}

// ---------------- BN stats (sum, sumsq per channel) ----------------
__global__ __launch_bounds__(256) void k_bnstats(const float* __restrict__ x,
                                                 float* __restrict__ sums, int N) {
  int c = threadIdx.x;
  float s = 0.f, sq = 0.f;
  for (int n = blockIdx.x; n < N; n += gridDim.x) {
    float v = x[(size_t)n * DIMX + c];
    s += v; sq += v * v;
  }
  atomicAdd(&sums[c], s);
  atomicAdd(&sums[DIMX + c], sq);
}

// ---------------- BN + leaky_relu(0.01) + residual (+ bf16 shadow) ----------------
template <bool FINAL>
__global__ __launch_bounds__(256) void k_bnapply(const float* __restrict__ x,
                                                 const float* __restrict__ res,
                                                 const float* __restrict__ sums,
                                                 const float* __restrict__ g,
                                                 const float* __restrict__ b,
                                                 void* __restrict__ out,
                                                 unsigned short* __restrict__ outb, int N,
                                                 const int* __restrict__ flag) {
  int i = blockIdx.x * 256 + threadIdx.x;
  if (i >= N * DIMX) return;
  int c = i & (DIMX - 1);
  float invn = 1.f / (float)N;
  float mu = sums[c] * invn;
  float var = sums[DIMX + c] * invn - mu * mu;
  float rstd = rsqrtf(var + 1e-5f);
  float y = (x[i] - mu) * rstd * g[c] + b[c];
  y = y > 0.f ? y : 0.01f * y;
  y += res[i];
  if (FINAL) {
    if (flag[0]) ((float*)out)[i] = y;
    else ((unsigned short*)out)[i] = f2b(y);
  } else {
    ((float*)out)[i] = y;
    outb[i] = f2b(y);
  }
}

extern "C" void kernel_launch(void* const* d_in, const int* in_sizes, int n_in,
                              void* d_out, int out_size, void* d_ws, size_t ws_size,
                              hipStream_t stream) {
  (void)in_sizes; (void)n_in; (void)out_size; (void)ws_size;
  const int* ei = (const int*)d_in[1];
  const int* srcp = ei;
  const int* dstp = ei + NE;

  char* w = (char*)d_ws;
  auto alloc = [&](size_t bytes) {
    char* p = w;
    w += (bytes + 255) & ~(size_t)255;
    return p;
  };
  float* H0 = (float*)alloc((size_t)NN * DIMX * 4);
  float* H1 = (float*)alloc((size_t)NN * DIMX * 4);
  float* G = (float*)alloc((size_t)NN * DIMX * 4);
  float* LEA = (float*)alloc((size_t)NN * EDIMX * 4);
  float* EWF = (float*)alloc((size_t)NE * EDIMX * 4);  // only used as FF1b alias now
  float* PAR = (float*)alloc((size_t)806656 * 4);
  float* SCORE = (float*)alloc((size_t)TOT * NHEADS * 4);  // unused now (kept for layout)
  int* CNT = (int*)alloc((size_t)NN * 4);
  int* ROWPTR = (int*)alloc((size_t)(NN + 1) * 4);
  int* FILL = (int*)alloc((size_t)NN * 4);
  int* EIDX = (int*)alloc((size_t)TOT * 4);
  int* SRCP = (int*)alloc((size_t)TOT * 4);
  int* DSTP = (int*)alloc((size_t)TOT * 4);
  float* BNS = (float*)alloc(2 * DIMX * 4);
  int* FLAG = (int*)alloc(256);
  unsigned short* H0b = (unsigned short*)alloc((size_t)NN * DIMX * 2);
  unsigned short* H1b = (unsigned short*)alloc((size_t)NN * DIMX * 2);
  unsigned short* XLRb = (unsigned short*)alloc((size_t)NN * 512 * 2);  // [xl|xr] per node
  unsigned short* EAB = (unsigned short*)alloc((size_t)TOT * EDIMX * 2);
  unsigned short* WLRT0 = (unsigned short*)alloc((size_t)512 * DIMX * 2);  // [Wl^T;Wr^T]
  unsigned short* WLRT1 = (unsigned short*)alloc((size_t)512 * DIMX * 2);
  unsigned short* WET0 = (unsigned short*)alloc((size_t)DIMX * EDIMX * 2);  // We^T [256][32]
  unsigned short* WET1 = (unsigned short*)alloc((size_t)DIMX * EDIMX * 2);
  unsigned short* W1T = (unsigned short*)alloc((size_t)DIMX * DFFX * 2);
  unsigned short* W2T = (unsigned short*)alloc((size_t)DFFX * DIMX * 2);
  unsigned short* FF1b = (unsigned short*)EWF;  // 41 MB alias, FF phase only
  (void)SCORE;

  // ---- dtype detect + convert params to f32 / activations to f32+bf16 ----
  k_detect<<<1, 256, 0, stream>>>((const unsigned short*)d_in[0], FLAG);
  k_cvt_dual<<<(NN * DIMX + 255) / 256, 256, 0, stream>>>(d_in[0], H0, H0b, NN * DIMX, FLAG);
  static const int psz[20] = {65536, 65536, 8192, 256, 256,
                              65536, 65536, 8192, 256, 256,
                              256, 256, 256, 256, 256, 256,
                              262144, 1024, 262144, 256};
  float* pp[20];
  {
    CvtArgs ca;
    int off = 0;
    for (int i = 0; i < 20; i++) {
      pp[i] = PAR + off;
      off += psz[i];
      ca.src[i] = d_in[3 + i];
      ca.dst[i] = pp[i];
      ca.n[i] = psz[i];
    }
    k_cvt_multi<<<dim3(262144 / 256, 20), 256, 0, stream>>>(ca, FLAG);
  }
  const float* g_att[2] = {pp[3], pp[8]};
  const float* g_b[2] = {pp[4], pp[9]};
  const float* bn_g[3] = {pp[10], pp[12], pp[14]};
  const float* bn_b[3] = {pp[11], pp[13], pp[15]};
  const float* ff_b1 = pp[17];
  const float* ff_b2 = pp[19];

  // ---- weights: bf16 [N][K] transposes; Wl/Wr stacked into one [512][256] ----
  k_transpose<<<dim3(8, 8), 256, 0, stream>>>(pp[0], WLRT0, DIMX, DIMX);
  k_transpose<<<dim3(8, 8), 256, 0, stream>>>(pp[1], WLRT0 + 256 * DIMX, DIMX, DIMX);
  k_transpose<<<dim3(8, 8), 256, 0, stream>>>(pp[5], WLRT1, DIMX, DIMX);
  k_transpose<<<dim3(8, 8), 256, 0, stream>>>(pp[6], WLRT1 + 256 * DIMX, DIMX, DIMX);
  k_transpose<<<dim3(8, 1), 256, 0, stream>>>(pp[2], WET0, EDIMX, DIMX);
  k_transpose<<<dim3(8, 1), 256, 0, stream>>>(pp[7], WET1, EDIMX, DIMX);
  k_transpose<<<dim3(32, 8), 256, 0, stream>>>(pp[16], W1T, DIMX, DFFX);
  k_transpose<<<dim3(8, 32), 256, 0, stream>>>(pp[18], W2T, DFFX, DIMX);
  const unsigned short* WLRT[2] = {WLRT0, WLRT1};
  const unsigned short* WET[2] = {WET0, WET1};

  // ---- graph structure (shared by both GAT layers) ----
  hipMemsetAsync(CNT, 0, (size_t)NN * 4, stream);
  hipMemsetAsync(FILL, 0, (size_t)NN * 4, stream);
  k_edge_count<<<(NE + 255) / 256, 256, 0, stream>>>(dstp, CNT, NE);
  k_scan<<<1, 256, 0, stream>>>(CNT, ROWPTR, NN);
  k_fill<<<(TOT + 255) / 256, 256, 0, stream>>>(dstp, ROWPTR, FILL, EIDX, DSTP, NN, NE);
  k_lea<<<(NN + 3) / 4, 256, 0, stream>>>(d_in[2], ROWPTR, EIDX, LEA, NN, FLAG);
  k_build_perm<<<(TOT + 7) / 8, 256, 0, stream>>>(EIDX, srcp, d_in[2], LEA, SRCP, EAB, TOT, NE,
                                                  FLAG);

  const int MBB = (NN + 127) / 128;  // 157
  auto run_gat = [&](const float* x, const unsigned short* xb, int li, int bi, float* hout,
                     unsigned short* houtb) {
    // XL|XR in one GEMM: N=512, K=256 (KTILES=8) -> grid (157, 4)
    k_gemm_lds<false, false, true, 8><<<dim3(MBB, 4), 256, 0, stream>>>(xb, WLRT[li], nullptr,
                                                                        XLRb, NN, 512);
    // fused score+softmax+aggregate, one wave per node
    k_gat_fused<<<(NN + 3) / 4, 256, 0, stream>>>(XLRb, EAB, SRCP, WET[li], g_att[li],
                                                  g_b[li], ROWPTR, G, NN);
    hipMemsetAsync(BNS, 0, 2 * DIMX * 4, stream);
    k_bnstats<<<128, 256, 0, stream>>>(G, BNS, NN);
    k_bnapply<false><<<(NN * DIMX + 255) / 256, 256, 0, stream>>>(G, x, BNS, bn_g[bi], bn_b[bi],
                                                                  hout, houtb, NN, FLAG);
  };

  run_gat(H0, H0b, 0, 0, H1, H1b);  // h1 = nf + lrelu(bn(gat1(nf)))
  run_gat(H1, H1b, 1, 1, H0, H0b);  // h2 = h1 + lrelu(bn(gat2(h1)))

  // ---- feed-forward ----
  // FF1: N=1024, K=256 (KTILES=8) -> grid (157, 8)
  k_gemm_lds<true, true, true, 8><<<dim3(MBB, 8), 256, 0, stream>>>(H0b, W1T, ff_b1, FF1b, NN,
                                                                    DFFX);
  // FF2: N=256, K=1024 (KTILES=32) -> grid (157, 2)
  k_gemm_lds<true, false, false, 32><<<dim3(MBB, 2), 256, 0, stream>>>(FF1b, W2T, ff_b2, G, NN,
                                                                       DIMX);
  hipMemsetAsync(BNS, 0, 2 * DIMX * 4, stream);
  k_bnstats<<<128, 256, 0, stream>>>(G, BNS, NN);
  k_bnapply<true><<<(NN * DIMX + 255) / 256, 256, 0, stream>>>(G, H0, BNS, bn_g[2], bn_b[2],
                                                               d_out, nullptr, NN, FLAG);
}

// Round 9
// 797.879 us; speedup vs baseline: 1.1510x; 1.1510x over previous
//
#include <hip/hip_runtime.h>

#define NN 20000
#define NE 320000
#define DIMX 256
#define NHEADS 8
#define HC 32
#define EDIMX 32
#define DFFX 1024
#define TOT (NE + NN)
#define NGROUPS (TOT / 16)  // 21250, exact

using f32x4 = __attribute__((ext_vector_type(4))) float;
using bfrag = __attribute__((ext_vector_type(8))) short;  // 8 bf16 = 4 VGPRs

__device__ __forceinline__ float b2f(unsigned short u) {
  return __uint_as_float(((unsigned)u) << 16);
}
__device__ __forceinline__ unsigned short f2b(float f) {
  unsigned u = __float_as_uint(f);
  u += 0x7FFF + ((u >> 16) & 1);
  return (unsigned short)(u >> 16);
}

// async global->LDS, 16B per lane; lds dest = wave-uniform base + lane*16
__device__ __forceinline__ void gload16(const unsigned short* g, unsigned short* l) {
  __builtin_amdgcn_global_load_lds(
      (const __attribute__((address_space(1))) unsigned int*)(g),
      (__attribute__((address_space(3))) unsigned int*)(l), 16, 0, 0);
}

// ---------------- dtype detect: 1 = inputs are f32, 0 = inputs are bf16 ----------------
__global__ void k_detect(const unsigned short* __restrict__ in, int* __restrict__ flag) {
  __shared__ int cnt_s;
  if (threadIdx.x == 0) cnt_s = 0;
  __syncthreads();
  int c = 0;
  for (int i = threadIdx.x; i < 4096; i += 256) {
    int ex = (in[i] >> 7) & 0xFF;
    if (ex >= 0xC6) c++;
  }
  atomicAdd(&cnt_s, c);
  __syncthreads();
  if (threadIdx.x == 0) flag[0] = (cnt_s > 64) ? 1 : 0;
}

// ---------------- input -> f32 + bf16 shadow ----------------
__global__ void k_cvt_dual(const void* __restrict__ in, float* __restrict__ outf,
                           unsigned short* __restrict__ outb, int n,
                           const int* __restrict__ flag) {
  int i = blockIdx.x * 256 + threadIdx.x;
  if (i >= n) return;
  if (flag[0]) {
    float v = ((const float*)in)[i];
    outf[i] = v;
    outb[i] = f2b(v);
  } else {
    unsigned short u = ((const unsigned short*)in)[i];
    outf[i] = b2f(u);
    outb[i] = u;
  }
}

// ---------------- fused multi-segment param convert ----------------
struct CvtArgs {
  const void* src[20];
  float* dst[20];
  int n[20];
};
__global__ void k_cvt_multi(CvtArgs a, const int* __restrict__ flag) {
  int seg = blockIdx.y;
  int n = a.n[seg];
  int i = blockIdx.x * 256 + threadIdx.x;
  if (i >= n) return;
  if (flag[0]) a.dst[seg][i] = ((const float*)a.src[seg])[i];
  else a.dst[seg][i] = b2f(((const unsigned short*)a.src[seg])[i]);
}

// ---------------- f32 [K][N] -> bf16 [N][K] transpose ----------------
__global__ __launch_bounds__(256) void k_transpose(const float* __restrict__ in,
                                                   unsigned short* __restrict__ out,
                                                   int K, int N) {
  __shared__ float t[32][33];
  int n0 = blockIdx.x * 32, k0 = blockIdx.y * 32;
  int tx = threadIdx.x & 31, ty = threadIdx.x >> 5;  // 32 x 8
#pragma unroll
  for (int i = 0; i < 4; i++)
    t[ty + i * 8][tx] = in[(size_t)(k0 + ty + i * 8) * N + n0 + tx];
  __syncthreads();
#pragma unroll
  for (int i = 0; i < 4; i++)
    out[(size_t)(n0 + ty + i * 8) * K + k0 + tx] = f2b(t[tx][ty + i * 8]);
}

// ---------------- edge count (int atomics only) ----------------
__global__ void k_edge_count(const int* __restrict__ dst, int* __restrict__ cnt, int E) {
  int e = blockIdx.x * 256 + threadIdx.x;
  if (e >= E) return;
  atomicAdd(&cnt[dst[e]], 1);
}

// ---------------- single-block scan -> rowptr ----------------
__global__ void k_scan(const int* __restrict__ cnt, int* __restrict__ rowptr, int N) {
  __shared__ int sums[256];
  int t = threadIdx.x;
  int chunk = (N + 255) / 256;
  int lo = t * chunk, hi = lo + chunk;
  if (hi > N) hi = N;
  if (lo > N) lo = N;
  int s = 0;
  for (int n = lo; n < hi; n++) s += cnt[n] + 1;
  sums[t] = s;
  __syncthreads();
  for (int off = 1; off < 256; off <<= 1) {
    int v = (t >= off) ? sums[t - off] : 0;
    __syncthreads();
    sums[t] += v;
    __syncthreads();
  }
  int run = sums[t] - s;  // exclusive prefix
  for (int n = lo; n < hi; n++) { rowptr[n] = run; run += cnt[n] + 1; }
  if (t == 255) rowptr[N] = run;
}

// ---------------- CSR fill (edges + self loops), also records dst per slot ----------------
__global__ void k_fill(const int* __restrict__ dst, const int* __restrict__ rowptr,
                       int* __restrict__ fill, int* __restrict__ eidx,
                       int* __restrict__ dstp, int N, int E) {
  int t = blockIdx.x * 256 + threadIdx.x;
  if (t < E) {
    int d = dst[t];
    int pos = rowptr[d] + atomicAdd(&fill[d], 1);
    eidx[pos] = t;
    dstp[pos] = d;
  } else if (t < E + N) {
    int n = t - E;
    int pos = rowptr[n + 1] - 1;
    eidx[pos] = E + n;  // self loop id
    dstp[pos] = n;
  }
}

// ---------------- loop_ea from raw ew input (flag-dispatched dtype) ----------------
__global__ __launch_bounds__(256) void k_lea(const void* __restrict__ ew,
                                             const int* __restrict__ rowptr,
                                             const int* __restrict__ eidx,
                                             float* __restrict__ lea, int N,
                                             const int* __restrict__ flag) {
  int f = flag[0];
  int wave = threadIdx.x >> 6, lane = threadIdx.x & 63;
  int node = blockIdx.x * 4 + wave;
  if (node >= N) return;
  int begin = rowptr[node], end = rowptr[node + 1] - 1;  // exclude self-loop slot
  int ch = lane & 31, half = lane >> 5;
  float s = 0.f;
  for (int p = begin + half; p < end; p += 2) {
    int eid = eidx[p];
    size_t idx = (size_t)eid * EDIMX + ch;
    s += f ? ((const float*)ew)[idx] : b2f(((const unsigned short*)ew)[idx]);
  }
  s += __shfl_xor(s, 32, 64);
  int deg = end - begin;
  if (lane < 32) lea[(size_t)node * EDIMX + ch] = s / (float)(deg > 0 ? deg : 1);
}

// ---------------- build CSR-ordered src ids + edge attrs (bf16) from raw ew ----------------
__global__ __launch_bounds__(256) void k_build_perm(const int* __restrict__ eidx,
                                                    const int* __restrict__ src,
                                                    const void* __restrict__ ew,
                                                    const float* __restrict__ lea,
                                                    int* __restrict__ srcp,
                                                    unsigned short* __restrict__ eab,
                                                    int total, int E,
                                                    const int* __restrict__ flag) {
  int f = flag[0];
  int g = blockIdx.x * 8 + (threadIdx.x >> 5);
  int lane = threadIdx.x & 31;
  if (g >= total) return;
  int eid = eidx[g];
  unsigned short v;
  int s;
  if (eid < E) {
    s = src[eid];
    size_t idx = (size_t)eid * EDIMX + lane;
    v = f ? f2b(((const float*)ew)[idx]) : ((const unsigned short*)ew)[idx];
  } else {
    s = eid - E;
    v = f2b(lea[(size_t)(eid - E) * EDIMX + lane]);
  }
  if (lane == 0) srcp[g] = s;
  eab[(size_t)g * EDIMX + lane] = v;
}

// ---------------- MFMA bf16 GEMM v3: m97 structure ----------------
template <bool BIAS, bool RELU, bool OUTBF16, int KTILES>
__global__ __launch_bounds__(256) void k_gemm_lds(const unsigned short* __restrict__ A,
                                                  const unsigned short* __restrict__ BT,
                                                  const float* __restrict__ bias,
                                                  void* __restrict__ C, int M, int N) {
  const int K = KTILES * 32;
  __shared__ unsigned short As[2][4096];  // [128 rows][32 bf16], 8KB per buf
  __shared__ unsigned short Bs[2][4096];
  int tid = threadIdx.x;
  int wave = tid >> 6, lane = tid & 63;
  int quad = lane >> 4, l16 = lane & 15;
  int wr = wave >> 1, wc = wave & 1;
  int bm0 = blockIdx.x * 128, bn0 = blockIdx.y * 128;
  int ch0 = wave * 2, ch1 = wave * 2 + 1;
  int sega = ch0 * 64 + lane, segb = ch1 * 64 + lane;
  int ra = sega >> 2, sa = sega & 3;
  int rb = segb >> 2, sb = segb & 3;
  int ca8 = sa ^ ((ra ^ (ra >> 2)) & 3);  // pre-swizzled source slot
  int cb8 = sb ^ ((rb ^ (rb >> 2)) & 3);
  int gra = bm0 + ra; if (gra > M - 1) gra = M - 1;
  int grb = bm0 + rb; if (grb > M - 1) grb = M - 1;
  const unsigned short* gA0 = A + (size_t)gra * K + ca8 * 8;
  const unsigned short* gA1 = A + (size_t)grb * K + cb8 * 8;
  const unsigned short* gB0 = BT + (size_t)(bn0 + ra) * K + ca8 * 8;
  const unsigned short* gB1 = BT + (size_t)(bn0 + rb) * K + cb8 * 8;
  f32x4 acc[4][4];
#pragma unroll
  for (int m = 0; m < 4; m++)
#pragma unroll
    for (int n = 0; n < 4; n++) acc[m][n] = (f32x4){0.f, 0.f, 0.f, 0.f};
  int sq = quad ^ ((l16 ^ (l16 >> 2)) & 3);
  int abase = (wr * 64 + l16) * 32 + sq * 8;
  int bbase = (wc * 64 + l16) * 32 + sq * 8;

  {  // stage tile 0
    gload16(gA0, &As[0][ch0 * 512]);
    gload16(gA1, &As[0][ch1 * 512]);
    gload16(gB0, &Bs[0][ch0 * 512]);
    gload16(gB1, &Bs[0][ch1 * 512]);
  }
  __syncthreads();
  int cur = 0;
  for (int t = 0; t < KTILES; ++t) {
    if (t + 1 < KTILES) {
      int ko = (t + 1) * 32;
      int nb = cur ^ 1;
      gload16(gA0 + ko, &As[nb][ch0 * 512]);
      gload16(gA1 + ko, &As[nb][ch1 * 512]);
      gload16(gB0 + ko, &Bs[nb][ch0 * 512]);
      gload16(gB1 + ko, &Bs[nb][ch1 * 512]);
    }
    bfrag af[4], bf[4];
#pragma unroll
    for (int m = 0; m < 4; m++) af[m] = *(const bfrag*)&As[cur][abase + m * 512];
#pragma unroll
    for (int n = 0; n < 4; n++) bf[n] = *(const bfrag*)&Bs[cur][bbase + n * 512];
#pragma unroll
    for (int m = 0; m < 4; m++)
#pragma unroll
      for (int n = 0; n < 4; n++)
        acc[m][n] = __builtin_amdgcn_mfma_f32_16x16x32_bf16(af[m], bf[n], acc[m][n], 0, 0, 0);
    __syncthreads();
    cur ^= 1;
  }
  int colb = bn0 + wc * 64;
  float bv[4];
#pragma unroll
  for (int n = 0; n < 4; n++) bv[n] = BIAS ? bias[colb + n * 16 + l16] : 0.f;
#pragma unroll
  for (int m = 0; m < 4; m++) {
    int row = bm0 + wr * 64 + m * 16 + quad * 4;
#pragma unroll
    for (int r = 0; r < 4; r++) {
      if (row + r < M) {
#pragma unroll
        for (int n = 0; n < 4; n++) {
          float v = acc[m][n][r] + bv[n];
          if (RELU) v = fmaxf(v, 0.f);
          int col = colb + n * 16 + l16;
          if (OUTBF16)
            ((unsigned short*)C)[(size_t)(row + r) * N + col] = f2b(v);
          else
            ((float*)C)[(size_t)(row + r) * N + col] = v;
        }
      }
    }
  }
}

// ---------------- fused GAT edge-score + softmax + aggregate v2 (scratch-free) ----------
// One wave per CSR row. ALL per-batch arrays written unconditionally (rule #20: conditional
// writes forced sc[]/vl[] to scratch -> 330MB spill traffic in v1). Invalid slots clamp to
// end-1 = a REAL edge, so batch-max needs no mask (duplicate of an included score); only
// l/o accumulation masks, via branchless value-select. (256,3) -> 170 VGPR cap, no spill.
__global__ __launch_bounds__(256, 3) void k_gat_fused(
    const unsigned short* __restrict__ xlr, const unsigned short* __restrict__ eab,
    const int* __restrict__ srcp, const unsigned short* __restrict__ WET,
    const float* __restrict__ att, const float* __restrict__ bias,
    const int* __restrict__ rowptr, float* __restrict__ out, int N) {
  __shared__ unsigned short ee_s[4][16 * 260];  // per-wave EE slice (33.3 KB)
  int wave = threadIdx.x >> 6, lane = threadIdx.x & 63;
  int quad = lane >> 4, l16 = lane & 15;
  int node = blockIdx.x * 4 + wave;
  if (node >= N) return;  // no barrier -> safe early exit
  int begin = rowptr[node], end = rowptr[node + 1];
  int deg = end - begin;  // >= 1 (self-loop)
  int c0 = lane * 4;
  ushort4 xru = *(const ushort4*)(xlr + ((size_t)node << 9) + 256 + c0);
  float xr0 = b2f(xru.x), xr1 = b2f(xru.y), xr2 = b2f(xru.z), xr3 = b2f(xru.w);
  float4 a4 = *(const float4*)(att + c0);
  float m = -3.4e38f, l = 0.f;
  float o0 = 0.f, o1 = 0.f, o2 = 0.f, o3 = 0.f;

  for (int b = 0; b < deg; b += 16) {
    int pb = begin + b;
    // wave-uniform src ids (clamped) -> SGPRs; unconditional
    int sid[16];
#pragma unroll
    for (int i = 0; i < 16; i++) {
      int q = pb + i;
      if (q > end - 1) q = end - 1;
      sid[i] = __builtin_amdgcn_readfirstlane(srcp[q]);
    }
    ushort4 vlA[8], vlB[8];
#pragma unroll
    for (int i = 0; i < 8; i++)
      vlA[i] = *(const ushort4*)(xlr + ((size_t)sid[i] << 9) + c0);
    int pe = pb + l16;
    if (pe > end - 1) pe = end - 1;
    const bfrag ea = *(const bfrag*)(eab + ((size_t)pe << 5) + quad * 8);
    f32x4 zero4 = {0.f, 0.f, 0.f, 0.f};
    __builtin_amdgcn_s_setprio(1);
#pragma unroll
    for (int tb = 0; tb < 4; tb++) {
      bfrag bw[4];
#pragma unroll
      for (int j = 0; j < 4; j++)
        bw[j] = *(const bfrag*)(WET + ((tb * 4 + j) * 16 + l16) * 32 + quad * 8);
      f32x4 a0 = __builtin_amdgcn_mfma_f32_16x16x32_bf16(ea, bw[0], zero4, 0, 0, 0);
      f32x4 a1 = __builtin_amdgcn_mfma_f32_16x16x32_bf16(ea, bw[1], zero4, 0, 0, 0);
      f32x4 a2 = __builtin_amdgcn_mfma_f32_16x16x32_bf16(ea, bw[2], zero4, 0, 0, 0);
      f32x4 a3 = __builtin_amdgcn_mfma_f32_16x16x32_bf16(ea, bw[3], zero4, 0, 0, 0);
#pragma unroll
      for (int r = 0; r < 4; r++) {
        int row = (quad * 4 + r) * 260 + l16;
        ee_s[wave][row + (tb * 4 + 0) * 16] = f2b(a0[r]);
        ee_s[wave][row + (tb * 4 + 1) * 16] = f2b(a1[r]);
        ee_s[wave][row + (tb * 4 + 2) * 16] = f2b(a2[r]);
        ee_s[wave][row + (tb * 4 + 3) * 16] = f2b(a3[r]);
      }
    }
    __builtin_amdgcn_s_setprio(0);
#pragma unroll
    for (int i = 0; i < 8; i++)
      vlB[i] = *(const ushort4*)(xlr + ((size_t)sid[8 + i] << 9) + c0);
    // scores: ALL pairs computed unconditionally -> sc[] statically written
    float sc[16];
    auto pair = [&](int e, const ushort4& u0, const ushort4& u1, float& s0, float& s1) {
      ushort4 eu0 = *(const ushort4*)&ee_s[wave][e * 260 + c0];
      ushort4 eu1 = *(const ushort4*)&ee_s[wave][(e + 1) * 260 + c0];
      float z00 = b2f(u0.x) + xr0 + b2f(eu0.x);
      float z01 = b2f(u0.y) + xr1 + b2f(eu0.y);
      float z02 = b2f(u0.z) + xr2 + b2f(eu0.z);
      float z03 = b2f(u0.w) + xr3 + b2f(eu0.w);
      float z10 = b2f(u1.x) + xr0 + b2f(eu1.x);
      float z11 = b2f(u1.y) + xr1 + b2f(eu1.y);
      float z12 = b2f(u1.z) + xr2 + b2f(eu1.z);
      float z13 = b2f(u1.w) + xr3 + b2f(eu1.w);
      z00 = fmaxf(z00, 0.2f * z00); z01 = fmaxf(z01, 0.2f * z01);
      z02 = fmaxf(z02, 0.2f * z02); z03 = fmaxf(z03, 0.2f * z03);
      z10 = fmaxf(z10, 0.2f * z10); z11 = fmaxf(z11, 0.2f * z11);
      z12 = fmaxf(z12, 0.2f * z12); z13 = fmaxf(z13, 0.2f * z13);
      float d0 = z00 * a4.x + z01 * a4.y + z02 * a4.z + z03 * a4.w;
      float d1 = z10 * a4.x + z11 * a4.y + z12 * a4.z + z13 * a4.w;
      d0 += __shfl_xor(d0, 1, 64);
      d1 += __shfl_xor(d1, 1, 64);
      d0 += __shfl_xor(d0, 2, 64);
      d1 += __shfl_xor(d1, 2, 64);
      d0 += __shfl_xor(d0, 4, 64);
      d1 += __shfl_xor(d1, 4, 64);
      s0 = d0;
      s1 = d1;
    };
    pair(0, vlA[0], vlA[1], sc[0], sc[1]);
    pair(2, vlA[2], vlA[3], sc[2], sc[3]);
    pair(4, vlA[4], vlA[5], sc[4], sc[5]);
    pair(6, vlA[6], vlA[7], sc[6], sc[7]);
    pair(8, vlB[0], vlB[1], sc[8], sc[9]);
    pair(10, vlB[2], vlB[3], sc[10], sc[11]);
    pair(12, vlB[4], vlB[5], sc[12], sc[13]);
    pair(14, vlB[6], vlB[7], sc[14], sc[15]);
    // batch max: unconditional (invalid slots duplicate a real score -> max unchanged)
    float bm = sc[0];
#pragma unroll
    for (int i = 1; i < 16; i++) bm = fmaxf(bm, sc[i]);
    float mn = fmaxf(m, bm);
    float f = __expf(m - mn);  // first batch: exp(-inf)=0
    o0 *= f; o1 *= f; o2 *= f; o3 *= f;
    l *= f;
    m = mn;
    // accumulate: branchless mask (write-unconditional value-select, wave-uniform cond)
#define ACCE(i, u)                                          \
  {                                                         \
    float wgt = (b + i < deg) ? __expf(sc[i] - m) : 0.f;    \
    l += wgt;                                               \
    o0 += wgt * b2f(u.x); o1 += wgt * b2f(u.y);             \
    o2 += wgt * b2f(u.z); o3 += wgt * b2f(u.w);             \
  }
    ACCE(0, vlA[0]) ACCE(1, vlA[1]) ACCE(2, vlA[2]) ACCE(3, vlA[3])
    ACCE(4, vlA[4]) ACCE(5, vlA[5]) ACCE(6, vlA[6]) ACCE(7, vlA[7])
    ACCE(8, vlB[0]) ACCE(9, vlB[1]) ACCE(10, vlB[2]) ACCE(11, vlB[3])
    ACCE(12, vlB[4]) ACCE(13, vlB[5]) ACCE(14, vlB[6]) ACCE(15, vlB[7])
#undef ACCE
  }
  float linv = 1.f / l;
  float4 bia = *(const float4*)(bias + c0);
  ((float4*)out)[(size_t)node * 64 + lane] =
      make_float4(o0 * linv + bia.x, o1 * linv + bia.y, o2 * linv + bia.z, o3 * linv + bia.w);
}

// ---------------- BN stats (sum, sumsq per channel) ----------------
__global__ __launch_bounds__(256) void k_bnstats(const float* __restrict__ x,
                                                 float* __restrict__ sums, int N) {
  int c = threadIdx.x;
  float s = 0.f, sq = 0.f;
  for (int n = blockIdx.x; n < N; n += gridDim.x) {
    float v = x[(size_t)n * DIMX + c];
    s += v; sq += v * v;
  }
  atomicAdd(&sums[c], s);
  atomicAdd(&sums[DIMX + c], sq);
}

// ---------------- BN + leaky_relu(0.01) + residual (+ bf16 shadow) ----------------
template <bool FINAL>
__global__ __launch_bounds__(256) void k_bnapply(const float* __restrict__ x,
                                                 const float* __restrict__ res,
                                                 const float* __restrict__ sums,
                                                 const float* __restrict__ g,
                                                 const float* __restrict__ b,
                                                 void* __restrict__ out,
                                                 unsigned short* __restrict__ outb, int N,
                                                 const int* __restrict__ flag) {
  int i = blockIdx.x * 256 + threadIdx.x;
  if (i >= N * DIMX) return;
  int c = i & (DIMX - 1);
  float invn = 1.f / (float)N;
  float mu = sums[c] * invn;
  float var = sums[DIMX + c] * invn - mu * mu;
  float rstd = rsqrtf(var + 1e-5f);
  float y = (x[i] - mu) * rstd * g[c] + b[c];
  y = y > 0.f ? y : 0.01f * y;
  y += res[i];
  if (FINAL) {
    if (flag[0]) ((float*)out)[i] = y;
    else ((unsigned short*)out)[i] = f2b(y);
  } else {
    ((float*)out)[i] = y;
    outb[i] = f2b(y);
  }
}

extern "C" void kernel_launch(void* const* d_in, const int* in_sizes, int n_in,
                              void* d_out, int out_size, void* d_ws, size_t ws_size,
                              hipStream_t stream) {
  (void)in_sizes; (void)n_in; (void)out_size; (void)ws_size;
  const int* ei = (const int*)d_in[1];
  const int* srcp = ei;
  const int* dstp = ei + NE;

  char* w = (char*)d_ws;
  auto alloc = [&](size_t bytes) {
    char* p = w;
    w += (bytes + 255) & ~(size_t)255;
    return p;
  };
  float* H0 = (float*)alloc((size_t)NN * DIMX * 4);
  float* H1 = (float*)alloc((size_t)NN * DIMX * 4);
  float* G = (float*)alloc((size_t)NN * DIMX * 4);
  float* LEA = (float*)alloc((size_t)NN * EDIMX * 4);
  float* EWF = (float*)alloc((size_t)NE * EDIMX * 4);  // only used as FF1b alias now
  float* PAR = (float*)alloc((size_t)806656 * 4);
  float* SCORE = (float*)alloc((size_t)TOT * NHEADS * 4);  // unused now (kept for layout)
  int* CNT = (int*)alloc((size_t)NN * 4);
  int* ROWPTR = (int*)alloc((size_t)(NN + 1) * 4);
  int* FILL = (int*)alloc((size_t)NN * 4);
  int* EIDX = (int*)alloc((size_t)TOT * 4);
  int* SRCP = (int*)alloc((size_t)TOT * 4);
  int* DSTP = (int*)alloc((size_t)TOT * 4);
  float* BNS = (float*)alloc(2 * DIMX * 4);
  int* FLAG = (int*)alloc(256);
  unsigned short* H0b = (unsigned short*)alloc((size_t)NN * DIMX * 2);
  unsigned short* H1b = (unsigned short*)alloc((size_t)NN * DIMX * 2);
  unsigned short* XLRb = (unsigned short*)alloc((size_t)NN * 512 * 2);  // [xl|xr] per node
  unsigned short* EAB = (unsigned short*)alloc((size_t)TOT * EDIMX * 2);
  unsigned short* WLRT0 = (unsigned short*)alloc((size_t)512 * DIMX * 2);  // [Wl^T;Wr^T]
  unsigned short* WLRT1 = (unsigned short*)alloc((size_t)512 * DIMX * 2);
  unsigned short* WET0 = (unsigned short*)alloc((size_t)DIMX * EDIMX * 2);  // We^T [256][32]
  unsigned short* WET1 = (unsigned short*)alloc((size_t)DIMX * EDIMX * 2);
  unsigned short* W1T = (unsigned short*)alloc((size_t)DIMX * DFFX * 2);
  unsigned short* W2T = (unsigned short*)alloc((size_t)DFFX * DIMX * 2);
  unsigned short* FF1b = (unsigned short*)EWF;  // 41 MB alias, FF phase only
  (void)SCORE;

  // ---- dtype detect + convert params to f32 / activations to f32+bf16 ----
  k_detect<<<1, 256, 0, stream>>>((const unsigned short*)d_in[0], FLAG);
  k_cvt_dual<<<(NN * DIMX + 255) / 256, 256, 0, stream>>>(d_in[0], H0, H0b, NN * DIMX, FLAG);
  static const int psz[20] = {65536, 65536, 8192, 256, 256,
                              65536, 65536, 8192, 256, 256,
                              256, 256, 256, 256, 256, 256,
                              262144, 1024, 262144, 256};
  float* pp[20];
  {
    CvtArgs ca;
    int off = 0;
    for (int i = 0; i < 20; i++) {
      pp[i] = PAR + off;
      off += psz[i];
      ca.src[i] = d_in[3 + i];
      ca.dst[i] = pp[i];
      ca.n[i] = psz[i];
    }
    k_cvt_multi<<<dim3(262144 / 256, 20), 256, 0, stream>>>(ca, FLAG);
  }
  const float* g_att[2] = {pp[3], pp[8]};
  const float* g_b[2] = {pp[4], pp[9]};
  const float* bn_g[3] = {pp[10], pp[12], pp[14]};
  const float* bn_b[3] = {pp[11], pp[13], pp[15]};
  const float* ff_b1 = pp[17];
  const float* ff_b2 = pp[19];

  // ---- weights: bf16 [N][K] transposes; Wl/Wr stacked into one [512][256] ----
  k_transpose<<<dim3(8, 8), 256, 0, stream>>>(pp[0], WLRT0, DIMX, DIMX);
  k_transpose<<<dim3(8, 8), 256, 0, stream>>>(pp[1], WLRT0 + 256 * DIMX, DIMX, DIMX);
  k_transpose<<<dim3(8, 8), 256, 0, stream>>>(pp[5], WLRT1, DIMX, DIMX);
  k_transpose<<<dim3(8, 8), 256, 0, stream>>>(pp[6], WLRT1 + 256 * DIMX, DIMX, DIMX);
  k_transpose<<<dim3(8, 1), 256, 0, stream>>>(pp[2], WET0, EDIMX, DIMX);
  k_transpose<<<dim3(8, 1), 256, 0, stream>>>(pp[7], WET1, EDIMX, DIMX);
  k_transpose<<<dim3(32, 8), 256, 0, stream>>>(pp[16], W1T, DIMX, DFFX);
  k_transpose<<<dim3(8, 32), 256, 0, stream>>>(pp[18], W2T, DFFX, DIMX);
  const unsigned short* WLRT[2] = {WLRT0, WLRT1};
  const unsigned short* WET[2] = {WET0, WET1};

  // ---- graph structure (shared by both GAT layers) ----
  hipMemsetAsync(CNT, 0, (size_t)NN * 4, stream);
  hipMemsetAsync(FILL, 0, (size_t)NN * 4, stream);
  k_edge_count<<<(NE + 255) / 256, 256, 0, stream>>>(dstp, CNT, NE);
  k_scan<<<1, 256, 0, stream>>>(CNT, ROWPTR, NN);
  k_fill<<<(TOT + 255) / 256, 256, 0, stream>>>(dstp, ROWPTR, FILL, EIDX, DSTP, NN, NE);
  k_lea<<<(NN + 3) / 4, 256, 0, stream>>>(d_in[2], ROWPTR, EIDX, LEA, NN, FLAG);
  k_build_perm<<<(TOT + 7) / 8, 256, 0, stream>>>(EIDX, srcp, d_in[2], LEA, SRCP, EAB, TOT, NE,
                                                  FLAG);

  const int MBB = (NN + 127) / 128;  // 157
  auto run_gat = [&](const float* x, const unsigned short* xb, int li, int bi, float* hout,
                     unsigned short* houtb) {
    // XL|XR in one GEMM: N=512, K=256 (KTILES=8) -> grid (157, 4)
    k_gemm_lds<false, false, true, 8><<<dim3(MBB, 4), 256, 0, stream>>>(xb, WLRT[li], nullptr,
                                                                        XLRb, NN, 512);
    // fused score+softmax+aggregate, one wave per node
    k_gat_fused<<<(NN + 3) / 4, 256, 0, stream>>>(XLRb, EAB, SRCP, WET[li], g_att[li],
                                                  g_b[li], ROWPTR, G, NN);
    hipMemsetAsync(BNS, 0, 2 * DIMX * 4, stream);
    k_bnstats<<<128, 256, 0, stream>>>(G, BNS, NN);
    k_bnapply<false><<<(NN * DIMX + 255) / 256, 256, 0, stream>>>(G, x, BNS, bn_g[bi], bn_b[bi],
                                                                  hout, houtb, NN, FLAG);
  };

  run_gat(H0, H0b, 0, 0, H1, H1b);  // h1 = nf + lrelu(bn(gat1(nf)))
  run_gat(H1, H1b, 1, 1, H0, H0b);  // h2 = h1 + lrelu(bn(gat2(h1)))

  // ---- feed-forward ----
  // FF1: N=1024, K=256 (KTILES=8) -> grid (157, 8)
  k_gemm_lds<true, true, true, 8><<<dim3(MBB, 8), 256, 0, stream>>>(H0b, W1T, ff_b1, FF1b, NN,
                                                                    DFFX);
  // FF2: N=256, K=1024 (KTILES=32) -> grid (157, 2)
  k_gemm_lds<true, false, false, 32><<<dim3(MBB, 2), 256, 0, stream>>>(FF1b, W2T, ff_b2, G, NN,
                                                                       DIMX);
  hipMemsetAsync(BNS, 0, 2 * DIMX * 4, stream);
  k_bnstats<<<128, 256, 0, stream>>>(G, BNS, NN);
  k_bnapply<true><<<(NN * DIMX + 255) / 256, 256, 0, stream>>>(G, H0, BNS, bn_g[2], bn_b[2],
                                                               d_out, nullptr, NN, FLAG);
}